// Round 9
// baseline (2621.329 us; speedup 1.0000x reference)
//
#include <hip/hip_runtime.h>
#include <stdint.h>

typedef uint16_t u16;
typedef uint32_t u32;
typedef unsigned long long u64;
typedef __attribute__((ext_vector_type(8))) __bf16 bf16x8;
typedef __attribute__((ext_vector_type(8))) short short8;
typedef __attribute__((ext_vector_type(4))) float floatx4;

// ---------- helpers ----------
__device__ __forceinline__ float bf2f(u16 u) {
  union { u32 i; float f; } v; v.i = ((u32)u) << 16; return v.f;
}
__device__ __forceinline__ u16 f2bf(float f) {
  union { float f; u32 i; } v; v.f = f;
  u32 i = v.i;
  return (u16)((i + 0x7FFFu + ((i >> 16) & 1u)) >> 16); // RTNE
}
__device__ __forceinline__ float sigm(float x) { return 1.f / (1.f + __expf(-x)); }
__device__ __forceinline__ float tanh_f(float x) {
  x = fminf(15.f, fmaxf(-15.f, x));
  float e = __expf(2.f * x);
  return (e - 1.f) / (e + 1.f);
}

// ---------- merged transpose: W/U/Wl f32 -> bf16 transposed, one launch ----------
__global__ __launch_bounds__(256) void transpose_all(
    const float* __restrict__ W, const float* __restrict__ U,
    const float* __restrict__ Wl,
    u16* __restrict__ WT, u16* __restrict__ UT, u16* __restrict__ WlT) {
  __shared__ u16 tile[32][33];
  int j = blockIdx.x;
  const float* src; u16* dst; int R, C, bx, by;
  if (j < 1024)      { src = U;  dst = UT;  R = 512; C = 2048; bx = j & 63; by = j >> 6; }
  else if (j < 1536) { j -= 1024; src = W;  dst = WT;  R = 256; C = 2048; bx = j & 63; by = j >> 6; }
  else               { j -= 1536; src = Wl; dst = WlT; R = 512; C = 256;  bx = j & 7;  by = j >> 3; }
  const int tx = threadIdx.x & 31, ty = threadIdx.x >> 5;
  int x = bx * 32 + tx;
#pragma unroll
  for (int jj = 0; jj < 4; ++jj) {
    int y = by * 32 + ty + jj * 8;
    tile[ty + jj * 8][tx] = f2bf(src[(size_t)y * C + x]);  // dims divide evenly
  }
  __syncthreads();
  int x2 = by * 32 + tx;
#pragma unroll
  for (int jj = 0; jj < 4; ++jj) {
    int y2 = bx * 32 + ty + jj * 8;
    dst[(size_t)y2 * R + x2] = tile[tx][ty + jj * 8];
  }
}

// ================== fused kernel: scan (blocks 0-15) + workers (16-255) ==================
// ROUND-9 CHANGE (single lever): the scan is re-packed as 16 blocks x 2 GROUP
// SLOTS. Block bi<16: pair=bi>>3 -> groups {2p,2p+1}, wgi=bi&7 (same 64
// h-cols for both slots -> U fragments SHARED). Per timestep: process slot A,
// then slot B -- group B's compute (~1us) hides group A's store->visible
// fabric latency (~1.5us), so each poll hits on the first sweep. Steady-state
// period = max(C_A+C_B, V) ~ 2.0-2.2us for BOTH groups vs 2.48us RT-bound.
// Exchange mechanism, hT_all layout, gates, epilogue: UNCHANGED (proven).
// Workers: 240 blocks (vs 224) -> chunk-0 xp ready sooner.
#define T_STEPS 512
#define HLSZ (16 * 520)
#define NWORK 240

#define LSTM_SLOT(GG, XPB, CST, HLSB, HPP, XC, XN, TT)                         \
  {                                                                            \
    const int t = (TT);                                                        \
    const int tn = (t + 1) & (T_STEPS - 1);                                    \
    /* gate: entering a new 64-step xp chunk -> wait for its producers */      \
    if (((tn) & 63) == 0 && t < T_STEPS - 1) {                                 \
      _Pragma("unroll")                                                        \
      for (int r = 0; r < 4; ++r) {                                            \
        const u32* cc = xpctr + (((GG) * 16 + q4 * 4 + r) * 8 + (tn >> 6));    \
        while (__hip_atomic_load(cc, __ATOMIC_RELAXED,                         \
                                 __HIP_MEMORY_SCOPE_AGENT) < 32u)              \
          __builtin_amdgcn_s_sleep(2);                                         \
      }                                                                        \
      __asm__ volatile("" ::: "memory");                                       \
    }                                                                          \
    /* prefetch next step's xp as RAW u16; consumed next step */               \
    _Pragma("unroll")                                                          \
    for (int qg = 0; qg < 4; ++qg)                                             \
      _Pragma("unroll")                                                        \
      for (int r = 0; r < 4; ++r)                                              \
        XN[qg * 4 + r] = (XPB)[((size_t)(q4 * 4 + r) * T_STEPS + tn) * 2048    \
                               + qg * 512 + cb + n];                           \
    __asm__ volatile("" ::: "memory");                                         \
    floatx4 acc[4] = {};                                                       \
    if (t > 0) {                                                               \
      const u64* hsrc = (const u64*)(hT_all)                                   \
                        + (size_t)((GG) * T_STEPS + (t - 1)) * 2048;           \
      u64 v[8];                                                                \
      for (;;) {                                                               \
        _Pragma("unroll")                                                      \
        for (int it = 0; it < 8; ++it)                                         \
          v[it] = __hip_atomic_load(hsrc + it * 256 + tid, __ATOMIC_RELAXED,   \
                                    __HIP_MEMORY_SCOPE_AGENT);                 \
        bool ok = true;                                                        \
        _Pragma("unroll")                                                      \
        for (int it = 0; it < 8; ++it) ok &= (v[it] != ~0ull);                 \
        if (ok) break;                                                         \
      }                                                                        \
      __asm__ volatile("" ::: "memory");                                       \
      u16* buf = (HLSB) + ((t - 1) & 1) * HLSZ;                                \
      _Pragma("unroll")                                                        \
      for (int it = 0; it < 8; ++it) {                                         \
        int idx = it * 256 + tid;                                              \
        int tile = idx >> 6, w = idx & 63;                                     \
        *(u64*)(buf + (w >> 2) * 520 + tile * 16 + (w & 3) * 4) = v[it];       \
      }                                                                        \
      __syncthreads();                                                         \
      _Pragma("unroll")                                                        \
      for (int kt = 0; kt < 16; ++kt) {                                        \
        bf16x8 a = *(const bf16x8*)(buf + n * 520 + kt * 32 + q4 * 8);         \
        acc[0] = __builtin_amdgcn_mfma_f32_16x16x32_bf16(a, u[0][kt], acc[0], 0, 0, 0); \
        acc[1] = __builtin_amdgcn_mfma_f32_16x16x32_bf16(a, u[1][kt], acc[1], 0, 0, 0); \
        acc[2] = __builtin_amdgcn_mfma_f32_16x16x32_bf16(a, u[2][kt], acc[2], 0, 0, 0); \
        acc[3] = __builtin_amdgcn_mfma_f32_16x16x32_bf16(a, u[3][kt], acc[3], 0, 0, 0); \
      }                                                                        \
    }                                                                          \
    _Pragma("unroll")                                                          \
    for (int r = 0; r < 4; ++r) {                                              \
      float gi = sigm(acc[0][r] + bf2f(XC[r]));                                \
      float gf = sigm(acc[1][r] + bf2f(XC[4 + r]));                            \
      float gg = tanh_f(acc[2][r] + bf2f(XC[8 + r]));                          \
      float go = sigm(acc[3][r] + bf2f(XC[12 + r]));                           \
      float cn = gf * (CST)[r] + gi * gg;                                      \
      (CST)[r] = cn;                                                           \
      float hv = go * tanh_f(cn);                                              \
      int row = q4 * 4 + r;                                                    \
      (HPP)[row * 16 + n] = f2bf(hv);                                          \
      if (t == T_STEPS - 1) {                                                  \
        out_hT[((GG) * 16 + row) * 512 + cb + n] = hv;                         \
        out_cT[((GG) * 16 + row) * 512 + cb + n] = cn;                         \
      }                                                                        \
    }                                                                          \
    __asm__ volatile("s_waitcnt lgkmcnt(0)" ::: "memory");                     \
    {                                                                          \
      u64 v = *(const u64*)((HPP) + (lane >> 2) * 16 + (lane & 3) * 4);        \
      u64* hdst = (u64*)(hT_all) + (size_t)((GG) * T_STEPS + t) * 2048         \
                  + p * 64 + lane;                                             \
      __hip_atomic_store(hdst, v, __ATOMIC_RELAXED, __HIP_MEMORY_SCOPE_AGENT); \
    }                                                                          \
  }

__global__ __launch_bounds__(256, 1) void fused_lstm(
    const float* __restrict__ x,    // [32768, 256] f32 (rows m = b*512 + t)
    const u16* __restrict__ WT,     // [2048, 256] bf16
    const float* __restrict__ bias, // [2048] f32
    u16* __restrict__ xp,           // [32768, 2048] bf16 (produced here)
    const u16* __restrict__ UT,     // [2048, 512] bf16
    u16* __restrict__ hT_all,       // [4][512][32][16][16] bf16, sentinel-filled
    const u16* __restrict__ WlT,    // [256, 512] bf16
    const float* __restrict__ bl,   // [256] f32
    float* __restrict__ outC,       // [32768, 256] f32 (permuted-row final out)
    float* __restrict__ out_hT,     // [64,512] f32
    float* __restrict__ out_cT,     // [64,512] f32
    u32* __restrict__ xpctr) {      // [64][8] job counters, zero-filled
  __shared__ __align__(16) u16 smem[4 * HLSZ + 8 * 256];  // 70.7 KB
  const int bi = blockIdx.x;
  const int tid = threadIdx.x;

  if (bi >= 16) {
    // =================== WORKER (round-7 proven, wid/NWORK updated) ===================
    u16* As = smem;
    u16* Bs = smem + 64 * 40;
    const int wid = bi - 16;
    const int wave = tid >> 6, lane = tid & 63;
    const int q4 = lane >> 4, n16 = lane & 15;
    const int mw = (wave >> 1) * 32, nw = (wave & 1) * 32;
    const int ldrow = tid >> 2, ldseg = (tid & 3) * 8;

    // ---- phase A: xp jobs, t-chunk-major ----
    for (int j = wid; j < 16384; j += NWORK) {
      const int tch = j >> 11;
      const int rem = j & 2047;
      const int b = rem >> 5, nt = rem & 31;
      const int m0 = b * 512 + tch * 64, n0 = nt * 64;
      floatx4 acc[2][2] = {};
      for (int k0 = 0; k0 < 256; k0 += 32) {
        const float* ap = x + (size_t)(m0 + ldrow) * 256 + k0 + ldseg;
        floatx4 a0 = *(const floatx4*)ap;
        floatx4 a1 = *(const floatx4*)(ap + 4);
        short8 s;
        s[0] = (short)f2bf(a0[0]); s[1] = (short)f2bf(a0[1]);
        s[2] = (short)f2bf(a0[2]); s[3] = (short)f2bf(a0[3]);
        s[4] = (short)f2bf(a1[0]); s[5] = (short)f2bf(a1[1]);
        s[6] = (short)f2bf(a1[2]); s[7] = (short)f2bf(a1[3]);
        *(short8*)(As + ldrow * 40 + ldseg) = s;
        *(short8*)(Bs + ldrow * 40 + ldseg) =
            *(const short8*)(WT + (size_t)(n0 + ldrow) * 256 + k0 + ldseg);
        __syncthreads();
#pragma unroll
        for (int mi = 0; mi < 2; ++mi) {
          bf16x8 a = *(const bf16x8*)(As + (mw + mi * 16 + n16) * 40 + q4 * 8);
#pragma unroll
          for (int ni = 0; ni < 2; ++ni) {
            bf16x8 bb = *(const bf16x8*)(Bs + (nw + ni * 16 + n16) * 40 + q4 * 8);
            acc[mi][ni] = __builtin_amdgcn_mfma_f32_16x16x32_bf16(a, bb, acc[mi][ni], 0, 0, 0);
          }
        }
        __syncthreads();
      }
      // epilogue: agent (write-through) stores so the scan's XCD sees them
#pragma unroll
      for (int mi = 0; mi < 2; ++mi)
#pragma unroll
        for (int ni = 0; ni < 2; ++ni) {
          int col = n0 + nw + ni * 16 + n16;
          float bv = bias[col];
#pragma unroll
          for (int r = 0; r < 4; ++r) {
            int m = m0 + mw + mi * 16 + q4 * 4 + r;
            u16 val = f2bf(acc[mi][ni][r] + bv);
            __hip_atomic_store(xp + (size_t)m * 2048 + col, val,
                               __ATOMIC_RELAXED, __HIP_MEMORY_SCOPE_AGENT);
          }
        }
      __asm__ volatile("s_waitcnt vmcnt(0)" ::: "memory");
      __syncthreads();
      if (tid == 0)
        __hip_atomic_fetch_add(xpctr + b * 8 + tch, 1u,
                               __ATOMIC_RELAXED, __HIP_MEMORY_SCOPE_AGENT);
    }

    // ---- phase B: final GEMM jobs, t-ascending ----
    for (int j = wid; j < 2048; j += NWORK) {
      const int tb = j >> 4, g2 = (j >> 2) & 3, nt = j & 3;
      const int m0 = g2 * 8192 + tb * 64, n0 = nt * 64;
      const int mm = m0 + ldrow;
      const size_t slot = ((size_t)((mm >> 13) * 512 + ((mm & 8191) >> 4))) * 8192
                          + (mm & 15) * 16;

      // ADVISORY slot-proxy gate: 1 thread polls the 32 tile-head u64s of the
      // job's highest-t slot. Scan writes every slot unconditionally -> terminates.
      if (tid == 0) {
        const u64* heads = (const u64*)(hT_all)
                           + (size_t)(g2 * T_STEPS + tb * 4 + 3) * 2048;
        for (;;) {
          bool ok = true;
#pragma unroll
          for (int p2 = 0; p2 < 32; ++p2)
            ok &= (__hip_atomic_load(heads + p2 * 64, __ATOMIC_RELAXED,
                                     __HIP_MEMORY_SCOPE_AGENT) != ~0ull);
          if (ok) break;
          __builtin_amdgcn_s_sleep(32);
        }
      }
      __syncthreads();

      floatx4 acc[2][2] = {};
      for (int k0 = 0; k0 < 512; k0 += 32) {
        int kk = k0 + ldseg;
        const u64* ap64 = (const u64*)(hT_all + slot + (kk >> 4) * 256 + (kk & 15));
        u64 lo, hi;
        for (;;) {
          lo = __hip_atomic_load(ap64, __ATOMIC_RELAXED, __HIP_MEMORY_SCOPE_AGENT);
          hi = __hip_atomic_load(ap64 + 1, __ATOMIC_RELAXED, __HIP_MEMORY_SCOPE_AGENT);
          if (lo != ~0ull && hi != ~0ull) break;
          __builtin_amdgcn_s_sleep(8);
        }
        *(u64*)(As + ldrow * 40 + ldseg) = lo;
        *(u64*)(As + ldrow * 40 + ldseg + 4) = hi;
        *(short8*)(Bs + ldrow * 40 + ldseg) =
            *(const short8*)(WlT + (size_t)(n0 + ldrow) * 512 + k0 + ldseg);
        __syncthreads();
#pragma unroll
        for (int mi = 0; mi < 2; ++mi) {
          bf16x8 a = *(const bf16x8*)(As + (mw + mi * 16 + n16) * 40 + q4 * 8);
#pragma unroll
          for (int ni = 0; ni < 2; ++ni) {
            bf16x8 bb = *(const bf16x8*)(Bs + (nw + ni * 16 + n16) * 40 + q4 * 8);
            acc[mi][ni] = __builtin_amdgcn_mfma_f32_16x16x32_bf16(a, bb, acc[mi][ni], 0, 0, 0);
          }
        }
        __syncthreads();
      }
#pragma unroll
      for (int mi = 0; mi < 2; ++mi)
#pragma unroll
        for (int ni = 0; ni < 2; ++ni) {
          int col = n0 + nw + ni * 16 + n16;
          float bv = bl[col];
#pragma unroll
          for (int r = 0; r < 4; ++r) {
            int m = m0 + mw + mi * 16 + q4 * 4 + r;
            int orow = ((m >> 13) * 16 + (m & 15)) * 512 + ((m & 8191) >> 4);
            outC[(size_t)orow * 256 + col] = acc[mi][ni][r] + bv;
          }
        }
    }
    return;
  }

  // =================== SCAN: 16 blocks x 2 group-slots ===================
  u16* hlsA = smem;                     // slot A parity-double-buffered stage
  u16* hlsB = smem + 2 * HLSZ;          // slot B stage
  u16* hstw = smem + 4 * HLSZ;          // 2 x per-wave 16x16 transpose patches
  const int pair = bi >> 3;             // 0..1
  const int wgi = bi & 7;
  const int gA = pair * 2, gB = pair * 2 + 1;
  const int wave = tid >> 6;
  const int lane = tid & 63;
  const int n = lane & 15;
  const int q4 = lane >> 4;
  const int cb = wgi * 64 + wave * 16;  // wave's h-col base (same for both slots)
  const int p = wgi * 4 + wave;         // tile index in group, 0..31
  u16* hpA = hstw + wave * 256;
  u16* hpB = hstw + 1024 + wave * 256;

  // Preload U fragments (B-operand layout) -- SHARED between slots
  bf16x8 u[4][16];
#pragma unroll
  for (int qg = 0; qg < 4; ++qg) {
    const u16* up = UT + (size_t)(qg * 512 + cb + n) * 512;
#pragma unroll
    for (int kt = 0; kt < 16; ++kt)
      u[qg][kt] = *(const bf16x8*)(up + kt * 32 + q4 * 8);
  }

  float cstA[4] = {0.f, 0.f, 0.f, 0.f};
  float cstB[4] = {0.f, 0.f, 0.f, 0.f};
  const u16* xpA = xp + (size_t)(gA * 16) * T_STEPS * 2048;
  const u16* xpB = xp + (size_t)(gB * 16) * T_STEPS * 2048;

  // prologue: gate on t-chunk 0 for both groups, then raw xp for t=0
#pragma unroll
  for (int r = 0; r < 4; ++r) {
    const u32* ccA = xpctr + ((gA * 16 + q4 * 4 + r) * 8 + 0);
    while (__hip_atomic_load(ccA, __ATOMIC_RELAXED, __HIP_MEMORY_SCOPE_AGENT) < 32u)
      __builtin_amdgcn_s_sleep(2);
    const u32* ccB = xpctr + ((gB * 16 + q4 * 4 + r) * 8 + 0);
    while (__hip_atomic_load(ccB, __ATOMIC_RELAXED, __HIP_MEMORY_SCOPE_AGENT) < 32u)
      __builtin_amdgcn_s_sleep(2);
  }
  __asm__ volatile("" ::: "memory");

  u16 xaA[16], xbA[16], xaB[16], xbB[16];
#pragma unroll
  for (int qg = 0; qg < 4; ++qg)
#pragma unroll
    for (int r = 0; r < 4; ++r) {
      xaA[qg * 4 + r] = xpA[((size_t)(q4 * 4 + r) * T_STEPS + 0) * 2048
                            + qg * 512 + cb + n];
      xaB[qg * 4 + r] = xpB[((size_t)(q4 * 4 + r) * T_STEPS + 0) * 2048
                            + qg * 512 + cb + n];
    }

#pragma unroll 1
  for (int t2 = 0; t2 < T_STEPS; t2 += 2) {
    LSTM_SLOT(gA, xpA, cstA, hlsA, hpA, xaA, xbA, t2)
    LSTM_SLOT(gB, xpB, cstB, hlsB, hpB, xaB, xbB, t2)
    LSTM_SLOT(gA, xpA, cstA, hlsA, hpA, xbA, xaA, t2 + 1)
    LSTM_SLOT(gB, xpB, cstB, hlsB, hpB, xbB, xaB, t2 + 1)
  }
}

// ---------- launch ----------
extern "C" void kernel_launch(void* const* d_in, const int* in_sizes, int n_in,
                              void* d_out, int out_size, void* d_ws, size_t ws_size,
                              hipStream_t stream) {
  (void)in_sizes; (void)n_in; (void)out_size; (void)ws_size;
  const float* x    = (const float*)d_in[0]; // [64,512,256] f32
  const float* W    = (const float*)d_in[1]; // [256,2048] f32
  const float* U    = (const float*)d_in[2]; // [512,2048] f32
  const float* bias = (const float*)d_in[3]; // [2048] f32
  const float* Wl   = (const float*)d_in[4]; // [512,256] f32
  const float* bl   = (const float*)d_in[5]; // [256] f32
  float* out = (float*)d_out;                // [64,512,256] ++ hT[64,512] ++ cT[64,512]
  char* ws = (char*)d_ws;

  u16* xp     = (u16*)(ws + 0);            // 134,217,728 B
  u16* UT     = (u16*)(ws + 134217728);    //   2,097,152 B
  u16* WT     = (u16*)(ws + 136314880);    //   1,048,576 B
  u16* WlT    = (u16*)(ws + 137363456);    //     262,144 B
  u16* hT_all = (u16*)(ws + 137625600);    //  33,554,432 B  [4][512][32][16][16]

  // ctr (2 KB) lives in the FIRST 2 KB of out_hT: dead after the scan's last
  // gate (t=448) and fully overwritten by the scan's t=511 epilogue.
  u32* ctr = (u32*)(out + 8388608);

  hipMemsetAsync(hT_all, 0xFF, 33554432, stream);  // sentinel (bf16 NaN)
  hipMemsetAsync(ctr, 0x00, 2048, stream);

  // one merged transpose launch (W^T, U^T, Wl^T)
  transpose_all<<<1664, 256, 0, stream>>>(W, U, Wl, WT, UT, WlT);

  // fused: scan (16 blocks x 2 slots) + workers (240 blocks)
  fused_lstm<<<256, 256, 0, stream>>>(x, WT, bias, xp, UT, hT_all, WlT, bl,
                                      out, out + 8388608, out + 8421376, ctr);
}

// Round 11
// 1424.292 us; speedup vs baseline: 1.8404x; 1.8404x over previous
//
#include <hip/hip_runtime.h>
#include <stdint.h>

typedef uint16_t u16;
typedef uint32_t u32;
typedef unsigned long long u64;
typedef __attribute__((ext_vector_type(8))) __bf16 bf16x8;
typedef __attribute__((ext_vector_type(8))) short short8;
typedef __attribute__((ext_vector_type(4))) float floatx4;

// ---------- helpers ----------
__device__ __forceinline__ float bf2f(u16 u) {
  union { u32 i; float f; } v; v.i = ((u32)u) << 16; return v.f;
}
__device__ __forceinline__ u16 f2bf(float f) {
  union { float f; u32 i; } v; v.f = f;
  u32 i = v.i;
  return (u16)((i + 0x7FFFu + ((i >> 16) & 1u)) >> 16); // RTNE
}
__device__ __forceinline__ float sigm(float x) { return 1.f / (1.f + __expf(-x)); }
__device__ __forceinline__ float tanh_f(float x) {
  x = fminf(15.f, fmaxf(-15.f, x));
  float e = __expf(2.f * x);
  return (e - 1.f) / (e + 1.f);
}

// ---------- merged transpose: W/U/Wl f32 -> bf16 transposed, one launch ----------
__global__ __launch_bounds__(256) void transpose_all(
    const float* __restrict__ W, const float* __restrict__ U,
    const float* __restrict__ Wl,
    u16* __restrict__ WT, u16* __restrict__ UT, u16* __restrict__ WlT) {
  __shared__ u16 tile[32][33];
  int j = blockIdx.x;
  const float* src; u16* dst; int R, C, bx, by;
  if (j < 1024)      { src = U;  dst = UT;  R = 512; C = 2048; bx = j & 63; by = j >> 6; }
  else if (j < 1536) { j -= 1024; src = W;  dst = WT;  R = 256; C = 2048; bx = j & 63; by = j >> 6; }
  else               { j -= 1536; src = Wl; dst = WlT; R = 512; C = 256;  bx = j & 7;  by = j >> 3; }
  const int tx = threadIdx.x & 31, ty = threadIdx.x >> 5;
  int x = bx * 32 + tx;
#pragma unroll
  for (int jj = 0; jj < 4; ++jj) {
    int y = by * 32 + ty + jj * 8;
    tile[ty + jj * 8][tx] = f2bf(src[(size_t)y * C + x]);  // dims divide evenly
  }
  __syncthreads();
  int x2 = by * 32 + tx;
#pragma unroll
  for (int jj = 0; jj < 4; ++jj) {
    int y2 = bx * 32 + ty + jj * 8;
    dst[(size_t)y2 * R + x2] = tile[tx][ty + jj * 8];
  }
}

// ================== fused kernel: scan (blocks 0-31) + workers (32-255) ==================
// ROUND-7 PROVEN STRUCTURE (session best: 1427 us total / 1368 us dispatch).
// Scan: round-0 exchange (agent-scope sentinel-poll on the h data itself,
// block-shared detection + LDS staging) + raw-xp double-buffer + xpctr gates.
// Workers phase A: xp = x@W + bias, t-chunk-major, agent stores, counter bumps.
// Workers phase B: out = hseq@Wl + bl, advisory slot-proxy gate (1 thread) +
// sentinel-validated data loads.
// REFUTED in this session (do not retry): per-wave direct-fragment polling
// (r3: 3.7x slower), sc0/L2 same-XCD exchange (r1-r3), scan-side progress
// publishing (r6), ping-pong h-poll (r8: vmcnt drains oldest-first, doubles
// the quantum), 16-block x 2-group-slot interleave (r9: cross-block dep ->
// period = 2V, ~2x slower).
#define T_STEPS 512
#define HLSZ (16 * 520)
#define NWORK 224

#define LSTM_STEP(XC, XN, TT)                                                  \
  {                                                                            \
    const int t = (TT);                                                        \
    const int tn = (t + 1) & (T_STEPS - 1);                                    \
    /* gate: entering a new 64-step xp chunk -> wait for its producers */      \
    if (((tn) & 63) == 0 && t < T_STEPS - 1) {                                 \
      _Pragma("unroll")                                                        \
      for (int r = 0; r < 4; ++r) {                                            \
        const u32* cc = xpctr + ((g * 16 + q4 * 4 + r) * 8 + (tn >> 6));       \
        while (__hip_atomic_load(cc, __ATOMIC_RELAXED,                         \
                                 __HIP_MEMORY_SCOPE_AGENT) < 32u)              \
          __builtin_amdgcn_s_sleep(2);                                         \
      }                                                                        \
      __asm__ volatile("" ::: "memory");                                       \
    }                                                                          \
    /* prefetch next step's xp as RAW u16; consumed next step */               \
    _Pragma("unroll")                                                          \
    for (int qg = 0; qg < 4; ++qg)                                             \
      _Pragma("unroll")                                                        \
      for (int r = 0; r < 4; ++r)                                              \
        XN[qg * 4 + r] = xp_base[((size_t)(q4 * 4 + r) * T_STEPS + tn) * 2048  \
                                 + qg * 512 + cb + n];                         \
    __asm__ volatile("" ::: "memory");                                         \
    floatx4 acc[4] = {};                                                       \
    if (t > 0) {                                                               \
      const u64* hsrc = (const u64*)(hT_all)                                   \
                        + (size_t)(g * T_STEPS + (t - 1)) * 2048;              \
      u64 v[8];                                                                \
      for (;;) {                                                               \
        _Pragma("unroll")                                                      \
        for (int it = 0; it < 8; ++it)                                         \
          v[it] = __hip_atomic_load(hsrc + it * 256 + tid, __ATOMIC_RELAXED,   \
                                    __HIP_MEMORY_SCOPE_AGENT);                 \
        bool ok = true;                                                        \
        _Pragma("unroll")                                                      \
        for (int it = 0; it < 8; ++it) ok &= (v[it] != ~0ull);                 \
        if (ok) break;                                                         \
      }                                                                        \
      __asm__ volatile("" ::: "memory");                                       \
      u16* buf = hls + ((t - 1) & 1) * HLSZ;                                   \
      _Pragma("unroll")                                                        \
      for (int it = 0; it < 8; ++it) {                                         \
        int idx = it * 256 + tid;                                              \
        int tile = idx >> 6, w = idx & 63;                                     \
        *(u64*)(buf + (w >> 2) * 520 + tile * 16 + (w & 3) * 4) = v[it];       \
      }                                                                        \
      __syncthreads();                                                         \
      _Pragma("unroll")                                                        \
      for (int kt = 0; kt < 16; ++kt) {                                        \
        bf16x8 a = *(const bf16x8*)(buf + n * 520 + kt * 32 + q4 * 8);         \
        acc[0] = __builtin_amdgcn_mfma_f32_16x16x32_bf16(a, u[0][kt], acc[0], 0, 0, 0); \
        acc[1] = __builtin_amdgcn_mfma_f32_16x16x32_bf16(a, u[1][kt], acc[1], 0, 0, 0); \
        acc[2] = __builtin_amdgcn_mfma_f32_16x16x32_bf16(a, u[2][kt], acc[2], 0, 0, 0); \
        acc[3] = __builtin_amdgcn_mfma_f32_16x16x32_bf16(a, u[3][kt], acc[3], 0, 0, 0); \
      }                                                                        \
    }                                                                          \
    _Pragma("unroll")                                                          \
    for (int r = 0; r < 4; ++r) {                                              \
      float gi = sigm(acc[0][r] + bf2f(XC[r]));                                \
      float gf = sigm(acc[1][r] + bf2f(XC[4 + r]));                            \
      float gg = tanh_f(acc[2][r] + bf2f(XC[8 + r]));                          \
      float go = sigm(acc[3][r] + bf2f(XC[12 + r]));                           \
      float cn = gf * cst[r] + gi * gg;                                        \
      cst[r] = cn;                                                             \
      float hv = go * tanh_f(cn);                                              \
      int row = q4 * 4 + r;                                                    \
      hp[row * 16 + n] = f2bf(hv);                                             \
      if (t == T_STEPS - 1) {                                                  \
        out_hT[(g * 16 + row) * 512 + cb + n] = hv;                            \
        out_cT[(g * 16 + row) * 512 + cb + n] = cn;                            \
      }                                                                        \
    }                                                                          \
    __asm__ volatile("s_waitcnt lgkmcnt(0)" ::: "memory");                     \
    {                                                                          \
      u64 v = *(const u64*)(hp + (lane >> 2) * 16 + (lane & 3) * 4);           \
      u64* hdst = (u64*)(hT_all) + (size_t)(g * T_STEPS + t) * 2048            \
                  + p * 64 + lane;                                             \
      __hip_atomic_store(hdst, v, __ATOMIC_RELAXED, __HIP_MEMORY_SCOPE_AGENT); \
    }                                                                          \
  }

__global__ __launch_bounds__(256, 1) void fused_lstm(
    const float* __restrict__ x,    // [32768, 256] f32 (rows m = b*512 + t)
    const u16* __restrict__ WT,     // [2048, 256] bf16
    const float* __restrict__ bias, // [2048] f32
    u16* __restrict__ xp,           // [32768, 2048] bf16 (produced here)
    const u16* __restrict__ UT,     // [2048, 512] bf16
    u16* __restrict__ hT_all,       // [4][512][32][16][16] bf16, sentinel-filled
    const u16* __restrict__ WlT,    // [256, 512] bf16
    const float* __restrict__ bl,   // [256] f32
    float* __restrict__ outC,       // [32768, 256] f32 (permuted-row final out)
    float* __restrict__ out_hT,     // [64,512] f32
    float* __restrict__ out_cT,     // [64,512] f32
    u32* __restrict__ xpctr) {      // [64][8] job counters, zero-filled
  __shared__ __align__(16) u16 smem[2 * HLSZ + 4 * 256];
  const int bi = blockIdx.x;
  const int tid = threadIdx.x;

  if (bi >= 32) {
    // =================== WORKER ===================
    u16* As = smem;
    u16* Bs = smem + 64 * 40;
    const int wid = bi - 32;
    const int wave = tid >> 6, lane = tid & 63;
    const int q4 = lane >> 4, n16 = lane & 15;
    const int mw = (wave >> 1) * 32, nw = (wave & 1) * 32;
    const int ldrow = tid >> 2, ldseg = (tid & 3) * 8;

    // ---- phase A: xp jobs, t-chunk-major ----
    for (int j = wid; j < 16384; j += NWORK) {
      const int tch = j >> 11;
      const int rem = j & 2047;
      const int b = rem >> 5, nt = rem & 31;
      const int m0 = b * 512 + tch * 64, n0 = nt * 64;
      floatx4 acc[2][2] = {};
      for (int k0 = 0; k0 < 256; k0 += 32) {
        const float* ap = x + (size_t)(m0 + ldrow) * 256 + k0 + ldseg;
        floatx4 a0 = *(const floatx4*)ap;
        floatx4 a1 = *(const floatx4*)(ap + 4);
        short8 s;
        s[0] = (short)f2bf(a0[0]); s[1] = (short)f2bf(a0[1]);
        s[2] = (short)f2bf(a0[2]); s[3] = (short)f2bf(a0[3]);
        s[4] = (short)f2bf(a1[0]); s[5] = (short)f2bf(a1[1]);
        s[6] = (short)f2bf(a1[2]); s[7] = (short)f2bf(a1[3]);
        *(short8*)(As + ldrow * 40 + ldseg) = s;
        *(short8*)(Bs + ldrow * 40 + ldseg) =
            *(const short8*)(WT + (size_t)(n0 + ldrow) * 256 + k0 + ldseg);
        __syncthreads();
#pragma unroll
        for (int mi = 0; mi < 2; ++mi) {
          bf16x8 a = *(const bf16x8*)(As + (mw + mi * 16 + n16) * 40 + q4 * 8);
#pragma unroll
          for (int ni = 0; ni < 2; ++ni) {
            bf16x8 bb = *(const bf16x8*)(Bs + (nw + ni * 16 + n16) * 40 + q4 * 8);
            acc[mi][ni] = __builtin_amdgcn_mfma_f32_16x16x32_bf16(a, bb, acc[mi][ni], 0, 0, 0);
          }
        }
        __syncthreads();
      }
      // epilogue: agent (write-through) stores so the scan's XCD sees them
#pragma unroll
      for (int mi = 0; mi < 2; ++mi)
#pragma unroll
        for (int ni = 0; ni < 2; ++ni) {
          int col = n0 + nw + ni * 16 + n16;
          float bv = bias[col];
#pragma unroll
          for (int r = 0; r < 4; ++r) {
            int m = m0 + mw + mi * 16 + q4 * 4 + r;
            u16 val = f2bf(acc[mi][ni][r] + bv);
            __hip_atomic_store(xp + (size_t)m * 2048 + col, val,
                               __ATOMIC_RELAXED, __HIP_MEMORY_SCOPE_AGENT);
          }
        }
      __asm__ volatile("s_waitcnt vmcnt(0)" ::: "memory");
      __syncthreads();
      if (tid == 0)
        __hip_atomic_fetch_add(xpctr + b * 8 + tch, 1u,
                               __ATOMIC_RELAXED, __HIP_MEMORY_SCOPE_AGENT);
    }

    // ---- phase B: final GEMM jobs, t-ascending ----
    for (int j = wid; j < 2048; j += NWORK) {
      const int tb = j >> 4, g2 = (j >> 2) & 3, nt = j & 3;
      const int m0 = g2 * 8192 + tb * 64, n0 = nt * 64;
      const int mm = m0 + ldrow;
      const size_t slot = ((size_t)((mm >> 13) * 512 + ((mm & 8191) >> 4))) * 8192
                          + (mm & 15) * 16;

      // ADVISORY slot-proxy gate: 1 thread polls the 32 tile-head u64s of the
      // job's highest-t slot (t_hi = tb*4+3). Scan writes every slot
      // unconditionally -> terminates. Cuts poll traffic ~30x vs data spin.
      if (tid == 0) {
        const u64* heads = (const u64*)(hT_all)
                           + (size_t)(g2 * T_STEPS + tb * 4 + 3) * 2048;
        for (;;) {
          bool ok = true;
#pragma unroll
          for (int p2 = 0; p2 < 32; ++p2)
            ok &= (__hip_atomic_load(heads + p2 * 64, __ATOMIC_RELAXED,
                                     __HIP_MEMORY_SCOPE_AGENT) != ~0ull);
          if (ok) break;
          __builtin_amdgcn_s_sleep(32);
        }
      }
      __syncthreads();

      floatx4 acc[2][2] = {};
      for (int k0 = 0; k0 < 512; k0 += 32) {
        int kk = k0 + ldseg;
        const u64* ap64 = (const u64*)(hT_all + slot + (kk >> 4) * 256 + (kk & 15));
        u64 lo, hi;
        for (;;) {
          lo = __hip_atomic_load(ap64, __ATOMIC_RELAXED, __HIP_MEMORY_SCOPE_AGENT);
          hi = __hip_atomic_load(ap64 + 1, __ATOMIC_RELAXED, __HIP_MEMORY_SCOPE_AGENT);
          if (lo != ~0ull && hi != ~0ull) break;
          __builtin_amdgcn_s_sleep(8);
        }
        *(u64*)(As + ldrow * 40 + ldseg) = lo;
        *(u64*)(As + ldrow * 40 + ldseg + 4) = hi;
        *(short8*)(Bs + ldrow * 40 + ldseg) =
            *(const short8*)(WlT + (size_t)(n0 + ldrow) * 512 + k0 + ldseg);
        __syncthreads();
#pragma unroll
        for (int mi = 0; mi < 2; ++mi) {
          bf16x8 a = *(const bf16x8*)(As + (mw + mi * 16 + n16) * 40 + q4 * 8);
#pragma unroll
          for (int ni = 0; ni < 2; ++ni) {
            bf16x8 bb = *(const bf16x8*)(Bs + (nw + ni * 16 + n16) * 40 + q4 * 8);
            acc[mi][ni] = __builtin_amdgcn_mfma_f32_16x16x32_bf16(a, bb, acc[mi][ni], 0, 0, 0);
          }
        }
        __syncthreads();
      }
#pragma unroll
      for (int mi = 0; mi < 2; ++mi)
#pragma unroll
        for (int ni = 0; ni < 2; ++ni) {
          int col = n0 + nw + ni * 16 + n16;
          float bv = bl[col];
#pragma unroll
          for (int r = 0; r < 4; ++r) {
            int m = m0 + mw + mi * 16 + q4 * 4 + r;
            int orow = ((m >> 13) * 16 + (m & 15)) * 512 + ((m & 8191) >> 4);
            outC[(size_t)orow * 256 + col] = acc[mi][ni][r] + bv;
          }
        }
    }
    return;
  }

  // =================== SCAN (round-0/4 proven structure + xpctr gates) ===================
  u16* hls = smem;                 // parity-double-buffered stage
  u16* hstw = smem + 2 * HLSZ;     // per-wave 16x16 transpose patch
  const int g = (bi & 7) >> 1;
  const int wgi = ((bi & 1) << 2) | (bi >> 3);
  const int wave = tid >> 6;
  const int lane = tid & 63;
  const int n = lane & 15;
  const int q4 = lane >> 4;
  const int cb = wgi * 64 + wave * 16;   // wave's h-col base
  const int p = wgi * 4 + wave;          // tile index in group, 0..31
  u16* hp = hstw + wave * 256;

  // Preload U fragments (B-operand layout)
  bf16x8 u[4][16];
#pragma unroll
  for (int qg = 0; qg < 4; ++qg) {
    const u16* up = UT + (size_t)(qg * 512 + cb + n) * 512;
#pragma unroll
    for (int kt = 0; kt < 16; ++kt)
      u[qg][kt] = *(const bf16x8*)(up + kt * 32 + q4 * 8);
  }

  float cst[4] = {0.f, 0.f, 0.f, 0.f};
  const u16* xp_base = xp + (size_t)(g * 16) * T_STEPS * 2048;

  // prologue: gate on t-chunk 0, then raw xp for t=0
#pragma unroll
  for (int r = 0; r < 4; ++r) {
    const u32* cc = xpctr + ((g * 16 + q4 * 4 + r) * 8 + 0);
    while (__hip_atomic_load(cc, __ATOMIC_RELAXED, __HIP_MEMORY_SCOPE_AGENT) < 32u)
      __builtin_amdgcn_s_sleep(2);
  }
  __asm__ volatile("" ::: "memory");

  u16 xa[16], xb[16];
#pragma unroll
  for (int qg = 0; qg < 4; ++qg)
#pragma unroll
    for (int r = 0; r < 4; ++r)
      xa[qg * 4 + r] = xp_base[((size_t)(q4 * 4 + r) * T_STEPS + 0) * 2048
                               + qg * 512 + cb + n];

#pragma unroll 1
  for (int t2 = 0; t2 < T_STEPS; t2 += 2) {
    LSTM_STEP(xa, xb, t2)
    LSTM_STEP(xb, xa, t2 + 1)
  }
}

// ---------- launch ----------
extern "C" void kernel_launch(void* const* d_in, const int* in_sizes, int n_in,
                              void* d_out, int out_size, void* d_ws, size_t ws_size,
                              hipStream_t stream) {
  (void)in_sizes; (void)n_in; (void)out_size; (void)ws_size;
  const float* x    = (const float*)d_in[0]; // [64,512,256] f32
  const float* W    = (const float*)d_in[1]; // [256,2048] f32
  const float* U    = (const float*)d_in[2]; // [512,2048] f32
  const float* bias = (const float*)d_in[3]; // [2048] f32
  const float* Wl   = (const float*)d_in[4]; // [512,256] f32
  const float* bl   = (const float*)d_in[5]; // [256] f32
  float* out = (float*)d_out;                // [64,512,256] ++ hT[64,512] ++ cT[64,512]
  char* ws = (char*)d_ws;

  u16* xp     = (u16*)(ws + 0);            // 134,217,728 B
  u16* UT     = (u16*)(ws + 134217728);    //   2,097,152 B
  u16* WT     = (u16*)(ws + 136314880);    //   1,048,576 B
  u16* WlT    = (u16*)(ws + 137363456);    //     262,144 B
  u16* hT_all = (u16*)(ws + 137625600);    //  33,554,432 B  [4][512][32][16][16]

  // ctr (2 KB) lives in the FIRST 2 KB of out_hT: dead after the scan's last
  // gate (t=448) and fully overwritten by the scan's t=511 epilogue.
  u32* ctr = (u32*)(out + 8388608);

  hipMemsetAsync(hT_all, 0xFF, 33554432, stream);  // sentinel (bf16 NaN)
  hipMemsetAsync(ctr, 0x00, 2048, stream);

  // one merged transpose launch (W^T, U^T, Wl^T)
  transpose_all<<<1664, 256, 0, stream>>>(W, U, Wl, WT, UT, WlT);

  // fused: scan (32 blocks) + xp producers / final-GEMM consumers (224 blocks)
  fused_lstm<<<256, 256, 0, stream>>>(x, WT, bias, xp, UT, hT_all, WlT, bl,
                                      out, out + 8388608, out + 8421376, ctr);
}